// Round 1
// baseline (412.994 us; speedup 1.0000x reference)
//
#include <hip/hip_runtime.h>
#include <hip/hip_bf16.h>
#include <stdint.h>

#define HID    128
#define DT     0.1f
#define NITER  10
#define RT     64           // rows (b,q pairs) per tile
#define NT     256          // 4 waves
#define HSTR   136          // H row stride in bf16 elems (odd multiple of 16B)
#define NTILES 4096         // (65536*4)/RT
#define PGRID  768          // persistent: 3 blocks/CU * 256 CU
#define SCALE  2.885390081777927f   // 2*log2(e): folded into W1..3/b1..3

typedef __attribute__((ext_vector_type(8))) short bf16x8;   // MFMA A/B frag
typedef __attribute__((ext_vector_type(4))) float f32x4;    // MFMA C/D frag
typedef __attribute__((ext_vector_type(2))) unsigned int u32x2;
typedef __attribute__((ext_vector_type(4))) unsigned int u32x4;

struct alignas(16) Smem {
    uint16_t hA[RT * HSTR];     // activations [batch][hid] bf16
    uint16_t hB[RT * HSTR];
    uint16_t xb[RT * 8];        // X bf16 [row][8], cols 4..7 stay zero
    uint32_t w4f[4 * 64 * 4];   // W4 A-frags, [kt][lane] as uint4
    float    b1[HID], b2[HID], b3[HID];   // pre-scaled by SCALE
    float    kk[RT * 4];        // K of current iter (for final combine)
};

__device__ __forceinline__ uint16_t f2bf(float f) {
    uint32_t u = __float_as_uint(f);
    return (uint16_t)((u + 0x7fffu + ((u >> 16) & 1u)) >> 16);
}

__device__ __forceinline__ uint32_t pk2(float a, float b) {
    __hip_bfloat162 h = __float22bfloat162_rn(float2{a, b});
    return *reinterpret_cast<uint32_t*>(&h);
}

// y = 2*log2(e)*x already (scale folded into weights/bias):
// tanh(x) = 1 - 2/(2^y + 1).  1 exp2 + 1 rcp + 1 add + 1 fma.
__device__ __forceinline__ float tanh_pre(float y) {
    float e = __builtin_amdgcn_exp2f(y);
    return fmaf(-2.0f, __builtin_amdgcn_rcpf(e + 1.0f), 1.0f);
}

// uniform scalar load -> SGPR
__device__ __forceinline__ float uread(const float* p) {
    return __uint_as_float(__builtin_amdgcn_readfirstlane(__float_as_uint(*p)));
}

// dst = tanh(src @ W + bias), transposed MFMA. Wave owns M-slice of 32
// (2 m-tiles), covers all 64 batch rows (4 n-tiles). bias/W pre-scaled.
__device__ __forceinline__ void dense_mfma(
    const bf16x8 (&wf)[2][4], const float* __restrict__ bias,
    const uint16_t* __restrict__ src, uint16_t* __restrict__ dst,
    int w, int ln, int g)
{
    f32x4 acc[2][4];
    #pragma unroll
    for (int mt = 0; mt < 2; ++mt) {
        f32x4 bs = *(const f32x4*)&bias[w * 32 + mt * 16 + 4 * g];
        #pragma unroll
        for (int nt = 0; nt < 4; ++nt) acc[mt][nt] = bs;
    }
    __builtin_amdgcn_s_setprio(1);
    #pragma unroll
    for (int kt = 0; kt < 4; ++kt) {
        bf16x8 bfr[4];
        #pragma unroll
        for (int nt = 0; nt < 4; ++nt)
            bfr[nt] = *(const bf16x8*)&src[(nt * 16 + ln) * HSTR + kt * 32 + 8 * g];
        #pragma unroll
        for (int mt = 0; mt < 2; ++mt)
            #pragma unroll
            for (int nt = 0; nt < 4; ++nt)
                acc[mt][nt] = __builtin_amdgcn_mfma_f32_16x16x32_bf16(wf[mt][kt], bfr[nt], acc[mt][nt], 0, 0, 0);
    }
    __builtin_amdgcn_s_setprio(0);
    #pragma unroll
    for (int mt = 0; mt < 2; ++mt) {
        int hb = w * 32 + mt * 16 + 4 * g;
        #pragma unroll
        for (int nt = 0; nt < 4; ++nt) {
            int r = nt * 16 + ln;
            u32x2 p;
            p.x = pk2(tanh_pre(acc[mt][nt][0]), tanh_pre(acc[mt][nt][1]));
            p.y = pk2(tanh_pre(acc[mt][nt][2]), tanh_pre(acc[mt][nt][3]));
            *(u32x2*)&dst[r * HSTR + hb] = p;
        }
    }
}

__global__ __launch_bounds__(NT, 3) void pinn_irk_mfma(
    const float* __restrict__ x0g,
    const float* __restrict__ w1g, const float* __restrict__ b1g,
    const float* __restrict__ w2g, const float* __restrict__ b2g,
    const float* __restrict__ w3g, const float* __restrict__ b3g,
    const float* __restrict__ w4g, const float* __restrict__ b4g,
    const float* __restrict__ l1g, const float* __restrict__ l2g,
    const float* __restrict__ l3g, const float* __restrict__ l4g,
    const float* __restrict__ alg, const float* __restrict__ beg,
    float* __restrict__ outg)
{
    __shared__ Smem S;
    const int t    = threadIdx.x;
    const int lane = t & 63;
    const int w    = t >> 6;        // wave 0..3: owns hid slice [w*32, w*32+32)
    const int ln   = lane & 15;
    const int g    = lane >> 4;     // quad
    const bool owner = (g == 0);
    const int r_own  = w * 16 + ln; // batch row owned by this lane (if owner)

    // ---- uniform params -> SGPRs (off the per-iter critical path) ----
    const float L0 = uread(l1g), L1v = uread(l2g), L2v = uread(l3g), L3v = uread(l4g);
    const float B40 = uread(b4g), B41 = uread(b4g + 1);
    const float B42 = uread(b4g + 2), B43 = uread(b4g + 3);
    const float BE0 = uread(beg), BE1 = uread(beg + 1);
    const float BE2 = uread(beg + 2), BE3 = uread(beg + 3);
    float A[16];
    #pragma unroll
    for (int i = 0; i < 16; ++i)
        A[i] = uread(alg + i);

    // ---- stage biases (pre-scaled) / zero xb pad ----
    if (t < HID) {
        S.b1[t] = b1g[t] * SCALE;
        S.b2[t] = b2g[t] * SCALE;
        S.b3[t] = b3g[t] * SCALE;
    }
    {   // zero cols 4..7 of xb (cols 0..3 written by owner lanes)
        int r = t >> 2, c = 4 + (t & 3);
        S.xb[r * 8 + c] = 0;
    }
    // ---- stage W4 A-frags into LDS: [kt][lane] (UNscaled) ----
    {
        int kt = t >> 6, l = t & 63;
        int lns = l & 15, gs = l >> 4;
        uint32_t f[4];
        #pragma unroll
        for (int jj = 0; jj < 4; ++jj) {
            int k0 = kt * 32 + 8 * gs + 2 * jj;
            uint32_t lo = (lns < 4) ? (uint32_t)f2bf(w4g[k0 * 4 + lns]) : 0u;
            uint32_t hi = (lns < 4) ? (uint32_t)f2bf(w4g[(k0 + 1) * 4 + lns]) : 0u;
            f[jj] = lo | (hi << 16);
        }
        *(u32x4*)&S.w4f[t * 4] = (u32x4){f[0], f[1], f[2], f[3]};
    }

    // ---- weight fragments W1/W2/W3 (M-slice of 32 per wave), pre-scaled ----
    // A-frag of W^T: lane (ln,g), elem j -> W[k=kt*32+8g+j][m=w*32+mt*16+ln]
    bf16x8 w1f[2], w2f[2][4], w3f[2][4];
    {
        const int mcol = w * 32 + ln;
        #pragma unroll
        for (int mt = 0; mt < 2; ++mt) {
            bf16x8 f1;
            #pragma unroll
            for (int j = 0; j < 8; ++j) {
                int k = 8 * g + j;
                float v = (k < 4) ? w1g[k * HID + mcol + mt * 16] * SCALE : 0.0f;
                f1[j] = (short)f2bf(v);
            }
            w1f[mt] = f1;
            #pragma unroll
            for (int kt = 0; kt < 4; ++kt) {
                bf16x8 f2, f3;
                #pragma unroll
                for (int j = 0; j < 8; ++j) {
                    int k = kt * 32 + 8 * g + j;
                    f2[j] = (short)f2bf(w2g[k * HID + mcol + mt * 16] * SCALE);
                    f3[j] = (short)f2bf(w3g[k * HID + mcol + mt * 16] * SCALE);
                }
                w2f[mt][kt] = f2;
                w3f[mt][kt] = f3;
            }
        }
    }
    __syncthreads();

    // ==== persistent tile loop: 5-6 tiles of 64 rows per block ====
    for (int tile = blockIdx.x; tile < NTILES; tile += PGRID) {

        // ---- owner-lane state: X0 / X in registers; init xb ----
        float X0r[4] = {0.f, 0.f, 0.f, 0.f};
        float Xr[4]  = {0.f, 0.f, 0.f, 0.f};
        if (owner) {
            const float* xp = x0g + (tile * (RT / 4) + (r_own >> 2)) * 4;
            #pragma unroll
            for (int c = 0; c < 4; ++c) { X0r[c] = xp[c]; Xr[c] = X0r[c]; }
            u32x2 p;
            p.x = pk2(Xr[0], Xr[1]);
            p.y = pk2(Xr[2], Xr[3]);
            *(u32x2*)&S.xb[r_own * 8] = p;
        }
        __syncthreads();

        #pragma unroll 1
        for (int it = 0; it < NITER; ++it) {
            // ---- L1: hA = tanh(X @ W1 + b1), K padded 4->32 ----
            {
                f32x4 acc[2][4];
                #pragma unroll
                for (int mt = 0; mt < 2; ++mt) {
                    f32x4 bs = *(const f32x4*)&S.b1[w * 32 + mt * 16 + 4 * g];
                    #pragma unroll
                    for (int nt = 0; nt < 4; ++nt) acc[mt][nt] = bs;
                }
                bf16x8 bfr[4];
                #pragma unroll
                for (int nt = 0; nt < 4; ++nt) bfr[nt] = (bf16x8){0,0,0,0,0,0,0,0};
                if (g == 0) {
                    #pragma unroll
                    for (int nt = 0; nt < 4; ++nt)
                        bfr[nt] = *(const bf16x8*)&S.xb[(nt * 16 + ln) * 8];
                }
                __builtin_amdgcn_s_setprio(1);
                #pragma unroll
                for (int mt = 0; mt < 2; ++mt)
                    #pragma unroll
                    for (int nt = 0; nt < 4; ++nt)
                        acc[mt][nt] = __builtin_amdgcn_mfma_f32_16x16x32_bf16(w1f[mt], bfr[nt], acc[mt][nt], 0, 0, 0);
                __builtin_amdgcn_s_setprio(0);
                #pragma unroll
                for (int mt = 0; mt < 2; ++mt) {
                    int hb = w * 32 + mt * 16 + 4 * g;
                    #pragma unroll
                    for (int nt = 0; nt < 4; ++nt) {
                        int r = nt * 16 + ln;
                        u32x2 p;
                        p.x = pk2(tanh_pre(acc[mt][nt][0]), tanh_pre(acc[mt][nt][1]));
                        p.y = pk2(tanh_pre(acc[mt][nt][2]), tanh_pre(acc[mt][nt][3]));
                        *(u32x2*)&S.hA[r * HSTR + hb] = p;
                    }
                }
            }
            __syncthreads();

            // ---- L2 ----
            dense_mfma(w2f, S.b2, S.hA, S.hB, w, ln, g);
            __syncthreads();

            // ---- L3 ----
            dense_mfma(w3f, S.b3, S.hB, S.hA, w, ln, g);
            __syncthreads();

            // ---- L4 + K update + X update (owner lanes) ----
            {
                f32x4 acc = (f32x4){0.f, 0.f, 0.f, 0.f};
                __builtin_amdgcn_s_setprio(1);
                #pragma unroll
                for (int kt = 0; kt < 4; ++kt) {
                    bf16x8 wfr = *(const bf16x8*)&S.w4f[(kt * 64 + lane) * 4];
                    bf16x8 bfr = *(const bf16x8*)&S.hA[r_own * HSTR + kt * 32 + 8 * g];
                    acc = __builtin_amdgcn_mfma_f32_16x16x32_bf16(wfr, bfr, acc, 0, 0, 0);
                }
                __builtin_amdgcn_s_setprio(0);
                if (owner) {
                    float h0 = acc[0] + B40, h1 = acc[1] + B41;
                    float h2 = acc[2] + B42, h3 = acc[3] + B43;
                    float kv0 = -L0 * h2 - L1v * Xr[2];
                    float kv1 = -L0 * h3 - L1v * Xr[3];
                    float kv2 =  L2v * h0 + L3v * Xr[0];
                    float kv3 =  L2v * h1 + L3v * Xr[1];
                    *(f32x4*)&S.kk[r_own * 4] = (f32x4){kv0, kv1, kv2, kv3};
                    #pragma unroll
                    for (int c = 0; c < 4; ++c) {
                        float s = kv0 * A[c] + kv1 * A[4 + c]
                                + kv2 * A[8 + c] + kv3 * A[12 + c];
                        Xr[c] = fmaf(DT, s, X0r[c]);
                    }
                    u32x2 p;
                    p.x = pk2(Xr[0], Xr[1]);
                    p.y = pk2(Xr[2], Xr[3]);
                    *(u32x2*)&S.xb[r_own * 8] = p;
                }
            }
            __syncthreads();
        }

        // ---- final combine: X1 = X0 + dt * sum_q beta_q K[:,q,:] ----
        // (kk read here; next tile's first write to kk is 3 barriers away -> safe)
        if (t < RT) {
            int bb = t >> 2, i = t & 3;
            float s = BE0 * S.kk[(bb * 4 + 0) * 4 + i]
                    + BE1 * S.kk[(bb * 4 + 1) * 4 + i]
                    + BE2 * S.kk[(bb * 4 + 2) * 4 + i]
                    + BE3 * S.kk[(bb * 4 + 3) * 4 + i];
            int bglob = tile * (RT / 4) + bb;
            outg[bglob * 4 + i] = x0g[bglob * 4 + i] + DT * s;
        }
        // no barrier needed: next tile's xb write doesn't touch kk, and the
        // tile-top __syncthreads orders xb for the next L1.
    }
}

extern "C" void kernel_launch(void* const* d_in, const int* in_sizes, int n_in,
                              void* d_out, int out_size, void* d_ws, size_t ws_size,
                              hipStream_t stream) {
    (void)in_sizes; (void)n_in; (void)d_ws; (void)ws_size; (void)out_size;

    dim3 grid(PGRID);                // persistent: 3 blocks/CU x 256 CU
    dim3 block(NT);

    pinn_irk_mfma<<<grid, block, 0, stream>>>(
        (const float*)d_in[0],
        (const float*)d_in[1],  (const float*)d_in[2],
        (const float*)d_in[3],  (const float*)d_in[4],
        (const float*)d_in[5],  (const float*)d_in[6],
        (const float*)d_in[7],  (const float*)d_in[8],
        (const float*)d_in[9],  (const float*)d_in[10],
        (const float*)d_in[11], (const float*)d_in[12],
        (const float*)d_in[13], (const float*)d_in[14],
        (float*)d_out);
}